// Round 1
// 689.603 us; speedup vs baseline: 1.0183x; 1.0183x over previous
//
#include <hip/hip_runtime.h>
#include <float.h>

#define N_ROWS 65536
#define D_IN   128
#define DH     64
#define K_CB   2048

typedef const __attribute__((address_space(1))) void* gas_p;
typedef __attribute__((address_space(3))) void* las_p;
typedef _Float16 f16x8 __attribute__((ext_vector_type(8)));
typedef float    f32x4 __attribute__((ext_vector_type(4)));

// ---------------- K1: project 128 -> 64, emit 2-plane fp16 split -----------
// z_ = h + m (11+11 mantissa-bit split, error ~2^-22 |v|); rows stored [n][64]
// with a 16B-chunk XOR swizzle: chunk c stored at c ^ (n&7) (bank-conflict-free
// MFMA frag reads after a LINEAR global_load_lds copy).
// blocks 0..4095: z rows (16/block); blocks 4096..4223: embedding rows + e2.
__global__ __launch_bounds__(256) void k_project(
    const float* __restrict__ Z, const float* __restrict__ emb,
    const float* __restrict__ W, const float* __restrict__ b,
    _Float16* __restrict__ zpl,   // [2][N_ROWS][64]
    _Float16* __restrict__ epl,   // [2][K_CB][64]
    float* __restrict__ e2) {
  __shared__ __align__(16) float Wl[64 * 140];   // stride 140: limits read conflicts
  __shared__ __align__(16) float Zl[16 * 128];
  int tid = threadIdx.x;
  const float* src; _Float16* dst; int n0; bool do_e2; size_t plane;
  if ((int)blockIdx.x < 4096) {
    src = Z;   dst = zpl; n0 = blockIdx.x * 16;          do_e2 = false; plane = (size_t)N_ROWS * 64;
  } else {
    src = emb; dst = epl; n0 = (blockIdx.x - 4096) * 16; do_e2 = true;  plane = (size_t)K_CB * 64;
  }

#pragma unroll
  for (int i = 0; i < 8; ++i) {
    int idx4 = tid + 256 * i;            // 0..2047 float4s
    int j = idx4 >> 5;
    int d4 = (idx4 & 31) * 4;
    *(float4*)&Wl[j * 140 + d4] = *(const float4*)(W + j * 128 + d4);
  }
#pragma unroll
  for (int i = 0; i < 2; ++i) {
    int idx4 = tid + 256 * i;            // 0..511 float4s
    int r = idx4 >> 5;
    int d4 = (idx4 & 31) * 4;
    *(float4*)&Zl[r * 128 + d4] = *(const float4*)(src + (size_t)(n0 + r) * 128 + d4);
  }
  int j = tid & 63, g = tid >> 6;        // j = output dim, g = wave -> 4 rows
  float bj = b[j];
  __syncthreads();

  float acc[4] = {0.f, 0.f, 0.f, 0.f};
  for (int d4 = 0; d4 < 128; d4 += 4) {
    float4 w4 = *(float4*)&Wl[j * 140 + d4];
#pragma unroll
    for (int i = 0; i < 4; ++i) {
      float4 z4 = *(float4*)&Zl[(g * 4 + i) * 128 + d4]; // wave-uniform broadcast
      acc[i] = fmaf(z4.x, w4.x, fmaf(z4.y, w4.y, fmaf(z4.z, w4.z, fmaf(z4.w, w4.w, acc[i]))));
    }
  }
#pragma unroll
  for (int i = 0; i < 4; ++i) {
    int n = n0 + g * 4 + i;
    float v = acc[i] + bj;
    _Float16 h = (_Float16)v;  float rm = v - (float)h;
    _Float16 m = (_Float16)rm;
    int pos = (((j >> 3) ^ (n & 7)) << 3) | (j & 7);   // 16B-chunk swizzle
    size_t base = (size_t)n * 64 + pos;
    dst[base]         = h;
    dst[plane + base] = m;
    if (do_e2) {
      float s = v * v;                   // exact fp32 ||e_||^2
#pragma unroll
      for (int off = 32; off > 0; off >>= 1) s += __shfl_xor(s, off, 64);
      if (j == 0) e2[n] = s;
    }
  }
}

// ---------------- K2: MFMA score + argmin + fused epilogue -----------------
// 64 z-rows/block, K-tile 128 cols. Wave w covers cols w*32..w*32+32.
// 4 fp16 MFMA passes (mm, mh, hm, hh) == fp32-accurate dot products.
// LDS: Zs 16KB + Es 32KB + e2s -> 3 blocks/CU.
__global__ __launch_bounds__(256, 3) void k_score(
    const _Float16* __restrict__ zpl,  // [2][N_ROWS][64] swizzled
    const _Float16* __restrict__ epl,  // [2][K_CB][64] swizzled
    const float* __restrict__ e2,      // [2048]
    const float* __restrict__ emb,     // [2048][128]
    float* __restrict__ outQ,
    float* __restrict__ outOH,         // null => fallback (write cidx_g)
    int* __restrict__ cidx_g) {
  __shared__ __align__(16) _Float16 Zs[2 * 64 * 64];    // 16 KB (planes @ 4096 elems)
  __shared__ __align__(16) _Float16 Es[2 * 128 * 64];   // 32 KB (planes @ 8192 elems)
  __shared__ float e2s[128];

  int tid = threadIdx.x, lane = tid & 63, wid = tid >> 6;
  int quad = lane >> 4, l16 = lane & 15;
  int wcol = wid * 32;
  int row0 = blockIdx.x * 64;

  // stage Z tile: 2 planes x 8KB, linear copies (swizzle already in global)
  for (int q = wid; q < 16; q += 4) {
    int p = q >> 3, within = (q & 7) * 1024;
    const char* g = (const char*)zpl + (size_t)p * ((size_t)N_ROWS * 128)
                  + (size_t)row0 * 128 + within + lane * 16;
    __builtin_amdgcn_global_load_lds((gas_p)g, (las_p)((char*)Zs + p * 8192 + within), 16, 0, 0);
  }

  float best[16]; int bidx[16];
#pragma unroll
  for (int s = 0; s < 16; ++s) { best[s] = FLT_MAX; bidx[s] = 0; }

  for (int kt = 0; kt < K_CB; kt += 128) {
    __syncthreads();                   // previous tile's Es readers done
    for (int q = wid; q < 32; q += 4) {
      int p = q >> 4, within = (q & 15) * 1024;
      const char* g = (const char*)epl + (size_t)p * (K_CB * 128)
                    + (size_t)kt * 128 + within + lane * 16;
      __builtin_amdgcn_global_load_lds((gas_p)g, (las_p)((char*)Es + p * 16384 + within), 16, 0, 0);
    }
    if (tid < 128) e2s[tid] = e2[kt + tid];
    __syncthreads();                   // drains vmcnt+lgkm: Es (and Zs at kt=0) ready

    // one_hot zeroing issued AFTER the drain barrier: its store-ack overlaps
    // the MFMA phase and is absorbed by the NEXT tile's first barrier.
    if (outOH) {
      float4 zz = make_float4(0.f, 0.f, 0.f, 0.f);
#pragma unroll
      for (int i = 0; i < 8; ++i) {
        int idx = tid + 256 * i;       // 0..2047 float4s
        int r = idx >> 5, c4 = (idx & 31) * 4;
        *(float4*)(outOH + (size_t)(row0 + r) * K_CB + kt + c4) = zz;
      }
    }

    f32x4 accf[4][2];
#pragma unroll
    for (int mt = 0; mt < 4; ++mt)
#pragma unroll
      for (int nt = 0; nt < 2; ++nt) accf[mt][nt] = (f32x4){0.f, 0.f, 0.f, 0.f};

#pragma unroll
    for (int step = 0; step < 2; ++step) {
      f16x8 A[4][2];
#pragma unroll
      for (int mt = 0; mt < 4; ++mt) {
        int tr = mt * 16 + l16;
        int cph = (step * 4 + quad) ^ (tr & 7);
        const _Float16* pa = Zs + tr * 64 + cph * 8;
        A[mt][0] = *(const f16x8*)pa;             // hi
        A[mt][1] = *(const f16x8*)(pa + 4096);    // mid
      }
#pragma unroll
      for (int nt = 0; nt < 2; ++nt) {
        int tc = wcol + nt * 16 + l16;
        int cph = (step * 4 + quad) ^ (tc & 7);
        const _Float16* pb = Es + tc * 64 + cph * 8;
        f16x8 Bh = *(const f16x8*)pb;
        f16x8 Bm = *(const f16x8*)(pb + 8192);
#pragma unroll
        for (int mt = 0; mt < 4; ++mt) {
          f32x4 c = accf[mt][nt];
          c = __builtin_amdgcn_mfma_f32_16x16x32_f16(A[mt][1], Bm, c, 0, 0, 0); // mm
          c = __builtin_amdgcn_mfma_f32_16x16x32_f16(A[mt][1], Bh, c, 0, 0, 0); // mh
          c = __builtin_amdgcn_mfma_f32_16x16x32_f16(A[mt][0], Bm, c, 0, 0, 0); // hm
          c = __builtin_amdgcn_mfma_f32_16x16x32_f16(A[mt][0], Bh, c, 0, 0, 0); // hh
          accf[mt][nt] = c;
        }
      }
    }

    // fold into running argmin (strict < + ascending kt => earliest index)
#pragma unroll
    for (int nt = 0; nt < 2; ++nt) {
      float ev = e2s[wcol + nt * 16 + l16];
      int col = kt + wcol + nt * 16 + l16;
#pragma unroll
      for (int mt = 0; mt < 4; ++mt)
#pragma unroll
        for (int r = 0; r < 4; ++r) {
          float s = fmaf(-2.0f, accf[mt][nt][r], ev);
          int slot = mt * 4 + r;
          if (s < best[slot]) { best[slot] = s; bidx[slot] = col; }
        }
    }
  }

  // cross-lane reduction: 64 rows x 64 (wave,l16) slots, reuse Es (32 KB)
  __syncthreads();
  float* redm = (float*)Es;                 // [64][64]
  int*   redi = (int*)((char*)Es + 16384);  // [64][64]
#pragma unroll
  for (int mt = 0; mt < 4; ++mt)
#pragma unroll
    for (int r = 0; r < 4; ++r) {
      int row = mt * 16 + quad * 4 + r;     // C-layout: row = quad*4 + reg
      redm[row * 64 + wid * 16 + l16] = best[mt * 4 + r];
      redi[row * 64 + wid * 16 + l16] = bidx[mt * 4 + r];
    }
  __syncthreads();
  int* cidx = (int*)Zs;
  if (tid < 64) {
    float m = redm[tid * 64]; int mi = redi[tid * 64];
    for (int s = 1; s < 64; ++s) {
      float v = redm[tid * 64 + s]; int vi = redi[tid * 64 + s];
      if (v < m || (v == m && vi < mi)) { m = v; mi = vi; }
    }
    cidx[tid] = mi;
  }
  __syncthreads();                     // vmcnt(0) drained: zeros visible pre-scatter

  if (outOH) {
    if (tid < 64) outOH[(size_t)(row0 + tid) * K_CB + cidx[tid]] = 1.0f;
  } else {
    if (tid < 64) cidx_g[row0 + tid] = cidx[tid];
  }

  // quantized gather (exact row copy; emb is L2-hot)
#pragma unroll
  for (int i = 0; i < 8; ++i) {
    int idx = tid + 256 * i;           // 0..2047 float4s
    int r = idx >> 5, c = (idx & 31) * 4;
    *(float4*)(outQ + (size_t)(row0 + r) * D_IN + c) =
        *(const float4*)(emb + (size_t)cidx[r] * D_IN + c);
  }
}

// ---------------- K3: fallback epilogue (zero one_hot + scatter) -----------
__global__ void k_epilogue(const int* __restrict__ cidx_g, float* __restrict__ outOH) {
  int tid  = threadIdx.x;
  int row0 = blockIdx.x * 64;
  float4 zz4 = make_float4(0.f, 0.f, 0.f, 0.f);
  for (int r = 0; r < 64; ++r) {
    float4* dst = (float4*)(outOH + (size_t)(row0 + r) * K_CB);
    dst[tid]       = zz4;
    dst[tid + 256] = zz4;
  }
  __syncthreads();
  if (tid < 64) {
    int r = row0 + tid;
    outOH[(size_t)r * K_CB + cidx_g[r]] = 1.0f;
  }
}

extern "C" void kernel_launch(void* const* d_in, const int* in_sizes, int n_in,
                              void* d_out, int out_size, void* d_ws, size_t ws_size,
                              hipStream_t stream) {
  (void)in_sizes; (void)n_in; (void)out_size;
  const float* Z   = (const float*)d_in[0];
  const float* W   = (const float*)d_in[1];
  const float* b   = (const float*)d_in[2];
  const float* emb = (const float*)d_in[3];
  float* outQ  = (float*)d_out;
  float* outOH = (float*)d_out + (size_t)N_ROWS * D_IN;

  // ws layout (bytes): epl 524288 | e2 8192 | (zpl 16777216  OR  cidx 262144)
  char* wsb = (char*)d_ws;
  _Float16* epl = (_Float16*)wsb;
  float*    e2  = (float*)(wsb + 524288);
  const size_t need_primary = 524288 + 8192 + (size_t)2 * N_ROWS * 64 * 2;

  if (ws_size >= need_primary) {
    _Float16* zpl = (_Float16*)(wsb + 532480);
    k_project<<<4224, 256, 0, stream>>>(Z, emb, W, b, zpl, epl, e2);
    k_score<<<1024, 256, 0, stream>>>(zpl, epl, e2, emb, outQ, outOH, nullptr);
  } else {
    // fallback: z planes live in the (not-yet-needed) one_hot region
    int*      cidx_g = (int*)(wsb + 532480);
    _Float16* zpl    = (_Float16*)outOH;
    k_project<<<4224, 256, 0, stream>>>(Z, emb, W, b, zpl, epl, e2);
    k_score<<<1024, 256, 0, stream>>>(zpl, epl, e2, emb, outQ, nullptr, cidx_g);
    k_epilogue<<<1024, 256, 0, stream>>>(cidx_g, outOH);
  }
}

// Round 3
// 674.458 us; speedup vs baseline: 1.0412x; 1.0225x over previous
//
#include <hip/hip_runtime.h>
#include <float.h>

#define N_ROWS 65536
#define D_IN   128
#define DH     64
#define K_CB   2048

typedef const __attribute__((address_space(1))) void* gas_p;
typedef __attribute__((address_space(3))) void* las_p;
typedef _Float16 f16x8 __attribute__((ext_vector_type(8)));
typedef float    f32x4 __attribute__((ext_vector_type(4)));

// ---------------- K1: project 128 -> 64, emit 2-plane fp16 split -----------
// z_ = h + m (11+11 mantissa-bit split, error ~2^-22 |v|); rows stored [n][64]
// with a 16B-chunk XOR swizzle: chunk c stored at c ^ (n&7) (bank-conflict-free
// MFMA frag reads after a LINEAR global_load_lds copy).
// blocks 0..4095: z rows (16/block) + zero the matching one_hot rows (128 KB,
// nontemporal, overlapped with compute); blocks 4096..4223: embedding rows + e2.
__global__ __launch_bounds__(256) void k_project(
    const float* __restrict__ Z, const float* __restrict__ emb,
    const float* __restrict__ W, const float* __restrict__ b,
    _Float16* __restrict__ zpl,   // [2][N_ROWS][64]
    _Float16* __restrict__ epl,   // [2][K_CB][64]
    float* __restrict__ e2,
    float* __restrict__ outOH) {  // non-null => zero one_hot rows here
  __shared__ __align__(16) float Wl[64 * 140];   // stride 140: limits read conflicts
  __shared__ __align__(16) float Zl[16 * 128];
  int tid = threadIdx.x;
  const float* src; _Float16* dst; int n0; bool do_e2; size_t plane;
  if ((int)blockIdx.x < 4096) {
    src = Z;   dst = zpl; n0 = blockIdx.x * 16;          do_e2 = false; plane = (size_t)N_ROWS * 64;
  } else {
    src = emb; dst = epl; n0 = (blockIdx.x - 4096) * 16; do_e2 = true;  plane = (size_t)K_CB * 64;
  }

#pragma unroll
  for (int i = 0; i < 8; ++i) {
    int idx4 = tid + 256 * i;            // 0..2047 float4s
    int j = idx4 >> 5;
    int d4 = (idx4 & 31) * 4;
    *(float4*)&Wl[j * 140 + d4] = *(const float4*)(W + j * 128 + d4);
  }
#pragma unroll
  for (int i = 0; i < 2; ++i) {
    int idx4 = tid + 256 * i;            // 0..511 float4s
    int r = idx4 >> 5;
    int d4 = (idx4 & 31) * 4;
    *(float4*)&Zl[r * 128 + d4] = *(const float4*)(src + (size_t)(n0 + r) * 128 + d4);
  }
  int j = tid & 63, g = tid >> 6;        // j = output dim, g = wave -> 4 rows
  float bj = b[j];
  __syncthreads();

  // one_hot zeroing AFTER the barrier: streams under the FMA loop, drains only
  // at kernel end (no barrier waits on these store acks).
  if (outOH && (int)blockIdx.x < 4096) {
    f32x4 zz4 = (f32x4){0.f, 0.f, 0.f, 0.f};
    f32x4* dz = (f32x4*)(outOH + (size_t)n0 * K_CB);   // 16 rows x 2048 = 8192 float4
#pragma unroll
    for (int i = 0; i < 32; ++i)
      __builtin_nontemporal_store(zz4, dz + tid + 256 * i);
  }

  float acc[4] = {0.f, 0.f, 0.f, 0.f};
  for (int d4 = 0; d4 < 128; d4 += 4) {
    float4 w4 = *(float4*)&Wl[j * 140 + d4];
#pragma unroll
    for (int i = 0; i < 4; ++i) {
      float4 z4 = *(float4*)&Zl[(g * 4 + i) * 128 + d4]; // wave-uniform broadcast
      acc[i] = fmaf(z4.x, w4.x, fmaf(z4.y, w4.y, fmaf(z4.z, w4.z, fmaf(z4.w, w4.w, acc[i]))));
    }
  }
#pragma unroll
  for (int i = 0; i < 4; ++i) {
    int n = n0 + g * 4 + i;
    float v = acc[i] + bj;
    _Float16 h = (_Float16)v;  float rm = v - (float)h;
    _Float16 m = (_Float16)rm;
    int pos = (((j >> 3) ^ (n & 7)) << 3) | (j & 7);   // 16B-chunk swizzle
    size_t base = (size_t)n * 64 + pos;
    dst[base]         = h;
    dst[plane + base] = m;
    if (do_e2) {
      float s = v * v;                   // exact fp32 ||e_||^2
#pragma unroll
      for (int off = 32; off > 0; off >>= 1) s += __shfl_xor(s, off, 64);
      if (j == 0) e2[n] = s;
    }
  }
}

// ---------------- K2: MFMA score + argmin + fused epilogue -----------------
// 64 z-rows/block, K-tile 128 cols. Wave w covers cols w*32..w*32+32.
// 4 fp16 MFMA passes (mm, mh, hm, hh) == fp32-accurate dot products.
// Tile loop has NO global stores: barriers wait only on the 32KB L2 staging.
// LDS: Zs 16KB + Es 32KB + e2s -> 3 blocks/CU.
__global__ __launch_bounds__(256, 3) void k_score(
    const _Float16* __restrict__ zpl,  // [2][N_ROWS][64] swizzled
    const _Float16* __restrict__ epl,  // [2][K_CB][64] swizzled
    const float* __restrict__ e2,      // [2048]
    const float* __restrict__ emb,     // [2048][128]
    float* __restrict__ outQ,
    float* __restrict__ outOH,         // null => fallback (write cidx_g)
    int* __restrict__ cidx_g) {
  __shared__ __align__(16) _Float16 Zs[2 * 64 * 64];    // 16 KB (planes @ 4096 elems)
  __shared__ __align__(16) _Float16 Es[2 * 128 * 64];   // 32 KB (planes @ 8192 elems)
  __shared__ float e2s[128];

  int tid = threadIdx.x, lane = tid & 63, wid = tid >> 6;
  int quad = lane >> 4, l16 = lane & 15;
  int wcol = wid * 32;
  int row0 = blockIdx.x * 64;

  // stage Z tile: 2 planes x 8KB, linear copies (swizzle already in global)
  for (int q = wid; q < 16; q += 4) {
    int p = q >> 3, within = (q & 7) * 1024;
    const char* g = (const char*)zpl + (size_t)p * ((size_t)N_ROWS * 128)
                  + (size_t)row0 * 128 + within + lane * 16;
    __builtin_amdgcn_global_load_lds((gas_p)g, (las_p)((char*)Zs + p * 8192 + within), 16, 0, 0);
  }

  float best[16]; int bidx[16];
#pragma unroll
  for (int s = 0; s < 16; ++s) { best[s] = FLT_MAX; bidx[s] = 0; }

  for (int kt = 0; kt < K_CB; kt += 128) {
    __syncthreads();                   // previous tile's Es readers done
    for (int q = wid; q < 32; q += 4) {
      int p = q >> 4, within = (q & 15) * 1024;
      const char* g = (const char*)epl + (size_t)p * (K_CB * 128)
                    + (size_t)kt * 128 + within + lane * 16;
      __builtin_amdgcn_global_load_lds((gas_p)g, (las_p)((char*)Es + p * 16384 + within), 16, 0, 0);
    }
    if (tid < 128) e2s[tid] = e2[kt + tid];
    __syncthreads();                   // drains vmcnt+lgkm: Es (and Zs at kt=0) ready

    f32x4 accf[4][2];
#pragma unroll
    for (int mt = 0; mt < 4; ++mt)
#pragma unroll
      for (int nt = 0; nt < 2; ++nt) accf[mt][nt] = (f32x4){0.f, 0.f, 0.f, 0.f};

#pragma unroll
    for (int step = 0; step < 2; ++step) {
      f16x8 A[4][2];
#pragma unroll
      for (int mt = 0; mt < 4; ++mt) {
        int tr = mt * 16 + l16;
        int cph = (step * 4 + quad) ^ (tr & 7);
        const _Float16* pa = Zs + tr * 64 + cph * 8;
        A[mt][0] = *(const f16x8*)pa;             // hi
        A[mt][1] = *(const f16x8*)(pa + 4096);    // mid
      }
#pragma unroll
      for (int nt = 0; nt < 2; ++nt) {
        int tc = wcol + nt * 16 + l16;
        int cph = (step * 4 + quad) ^ (tc & 7);
        const _Float16* pb = Es + tc * 64 + cph * 8;
        f16x8 Bh = *(const f16x8*)pb;
        f16x8 Bm = *(const f16x8*)(pb + 8192);
#pragma unroll
        for (int mt = 0; mt < 4; ++mt) {
          f32x4 c = accf[mt][nt];
          c = __builtin_amdgcn_mfma_f32_16x16x32_f16(A[mt][1], Bm, c, 0, 0, 0); // mm
          c = __builtin_amdgcn_mfma_f32_16x16x32_f16(A[mt][1], Bh, c, 0, 0, 0); // mh
          c = __builtin_amdgcn_mfma_f32_16x16x32_f16(A[mt][0], Bm, c, 0, 0, 0); // hm
          c = __builtin_amdgcn_mfma_f32_16x16x32_f16(A[mt][0], Bh, c, 0, 0, 0); // hh
          accf[mt][nt] = c;
        }
      }
    }

    // fold into running argmin (strict < + ascending kt => earliest index)
#pragma unroll
    for (int nt = 0; nt < 2; ++nt) {
      float ev = e2s[wcol + nt * 16 + l16];
      int col = kt + wcol + nt * 16 + l16;
#pragma unroll
      for (int mt = 0; mt < 4; ++mt)
#pragma unroll
        for (int r = 0; r < 4; ++r) {
          float s = fmaf(-2.0f, accf[mt][nt][r], ev);
          int slot = mt * 4 + r;
          if (s < best[slot]) { best[slot] = s; bidx[slot] = col; }
        }
    }
  }

  // cross-lane reduction: 64 rows x 64 (wave,l16) slots, reuse Es (32 KB)
  __syncthreads();
  float* redm = (float*)Es;                 // [64][64]
  int*   redi = (int*)((char*)Es + 16384);  // [64][64]
#pragma unroll
  for (int mt = 0; mt < 4; ++mt)
#pragma unroll
    for (int r = 0; r < 4; ++r) {
      int row = mt * 16 + quad * 4 + r;     // C-layout: row = quad*4 + reg
      redm[row * 64 + wid * 16 + l16] = best[mt * 4 + r];
      redi[row * 64 + wid * 16 + l16] = bidx[mt * 4 + r];
    }
  __syncthreads();
  int* cidx = (int*)Zs;
  if (tid < 64) {
    float m = redm[tid * 64]; int mi = redi[tid * 64];
    for (int s = 1; s < 64; ++s) {
      float v = redm[tid * 64 + s]; int vi = redi[tid * 64 + s];
      if (v < m || (v == m && vi < mi)) { m = v; mi = vi; }
    }
    cidx[tid] = mi;
  }
  __syncthreads();

  if (outOH) {
    // zeros were written by k_project (prior kernel on this stream => visible)
    if (tid < 64) outOH[(size_t)(row0 + tid) * K_CB + cidx[tid]] = 1.0f;
  } else {
    if (tid < 64) cidx_g[row0 + tid] = cidx[tid];
  }

  // quantized gather (exact row copy; emb is L2-hot); nontemporal: keep L2
  // for epl/zpl/emb.
#pragma unroll
  for (int i = 0; i < 8; ++i) {
    int idx = tid + 256 * i;           // 0..2047 float4s
    int r = idx >> 5, c = (idx & 31) * 4;
    f32x4 v = *(const f32x4*)(emb + (size_t)cidx[r] * D_IN + c);
    __builtin_nontemporal_store(v, (f32x4*)(outQ + (size_t)(row0 + r) * D_IN + c));
  }
}

// ---------------- K3: fallback epilogue (zero one_hot + scatter) -----------
__global__ void k_epilogue(const int* __restrict__ cidx_g, float* __restrict__ outOH) {
  int tid  = threadIdx.x;
  int row0 = blockIdx.x * 64;
  float4 zz4 = make_float4(0.f, 0.f, 0.f, 0.f);
  for (int r = 0; r < 64; ++r) {
    float4* dst = (float4*)(outOH + (size_t)(row0 + r) * K_CB);
    dst[tid]       = zz4;
    dst[tid + 256] = zz4;
  }
  __syncthreads();
  if (tid < 64) {
    int r = row0 + tid;
    outOH[(size_t)r * K_CB + cidx_g[r]] = 1.0f;
  }
}

extern "C" void kernel_launch(void* const* d_in, const int* in_sizes, int n_in,
                              void* d_out, int out_size, void* d_ws, size_t ws_size,
                              hipStream_t stream) {
  (void)in_sizes; (void)n_in; (void)out_size;
  const float* Z   = (const float*)d_in[0];
  const float* W   = (const float*)d_in[1];
  const float* b   = (const float*)d_in[2];
  const float* emb = (const float*)d_in[3];
  float* outQ  = (float*)d_out;
  float* outOH = (float*)d_out + (size_t)N_ROWS * D_IN;

  // ws layout (bytes): epl 524288 | e2 8192 | (zpl 16777216  OR  cidx 262144)
  char* wsb = (char*)d_ws;
  _Float16* epl = (_Float16*)wsb;
  float*    e2  = (float*)(wsb + 524288);
  const size_t need_primary = 524288 + 8192 + (size_t)2 * N_ROWS * 64 * 2;

  if (ws_size >= need_primary) {
    _Float16* zpl = (_Float16*)(wsb + 532480);
    k_project<<<4224, 256, 0, stream>>>(Z, emb, W, b, zpl, epl, e2, outOH);
    k_score<<<1024, 256, 0, stream>>>(zpl, epl, e2, emb, outQ, outOH, nullptr);
  } else {
    // fallback: z planes live in the (not-yet-needed) one_hot region;
    // k_project must NOT zero it (aliases zpl) -> k_epilogue zeroes later.
    int*      cidx_g = (int*)(wsb + 532480);
    _Float16* zpl    = (_Float16*)outOH;
    k_project<<<4224, 256, 0, stream>>>(Z, emb, W, b, zpl, epl, e2, nullptr);
    k_score<<<1024, 256, 0, stream>>>(zpl, epl, e2, emb, outQ, nullptr, cidx_g);
    k_epilogue<<<1024, 256, 0, stream>>>(cidx_g, outOH);
  }
}